// Round 15
// baseline (256.030 us; speedup 1.0000x reference)
//
#include <hip/hip_runtime.h>

// SioConvPS: fused init -> z/dt/g projections (bf16 MFMA GEMM, 128^2 tile,
// 8 waves, 2 blocks/CU for cross-block MFMA/LDS overlap (m114), r9-pattern
// 8-phase counted-vmcnt schedule) -> stable linear scan (8-deep prefetch) ->
// gated y GEMM.  Outputs (f32): d_out = [y (B,L,D), h (B,L,D)].

#define BDIM 4
#define LDIM 4096
#define DDIM 1024
#define MROWS (BDIM * LDIM)   // 16384
#define KDIM 1024
#define NPROJ 3072
#define NCHUNK 64             // chunks along L
#define LCHUNK 64             // LDIM / NCHUNK

typedef __attribute__((ext_vector_type(8))) short short8v;
typedef __attribute__((ext_vector_type(4))) float f32x4;
typedef unsigned int uint;

__device__ __forceinline__ float bf2f(short u) {
    union { float f; uint i; } v;
    v.i = ((uint)(unsigned short)u) << 16;
    return v.f;
}
__device__ __forceinline__ short f2bf(float f) {
    union { float f; uint i; } v; v.f = f;
    uint r = v.i + 0x7FFFu + ((v.i >> 16) & 1u);  // RNE
    return (short)(r >> 16);
}
__device__ __forceinline__ float sigf(float x) { return 1.f / (1.f + __expf(-x)); }

#define SCANSTEP(zz, dd, H0, H1, A0, A1, DO_A)                                     \
  {                                                                                \
    float _z0 = bf2f((short)((zz) & 0xffff)), _z1 = bf2f((short)((zz) >> 16));     \
    float _d0 = bf2f((short)((dd) & 0xffff)), _d1 = bf2f((short)((dd) >> 16));     \
    float _e0 = __expf(-_d0), _r0 = 1.f / (1.f + _e0);                             \
    float _o0 = _e0 * _r0, _q0 = sigf(_z0) * _r0;                                  \
    float _e1 = __expf(-_d1), _r1 = 1.f / (1.f + _e1);                             \
    float _o1 = _e1 * _r1, _q1 = sigf(_z1) * _r1;                                  \
    H0 = _q0 + _o0 * H0; H1 = _q1 + _o1 * H1;                                      \
    if (DO_A) { A0 *= _o0; A1 *= _o1; }                                            \
  }

// ---------------- fused init: x cast + 4 weight casts + bias concat ----------------
__global__ __launch_bounds__(256) void fused_init(
    const float* __restrict__ x,
    const float* __restrict__ W_ln_z, const float* __restrict__ W_dt,
    const float* __restrict__ W_g,    const float* __restrict__ W_y,
    const float* __restrict__ b_ln_z, const float* __restrict__ b_dt,
    const float* __restrict__ b_g,
    short* __restrict__ x_bf, short* __restrict__ Wcat, float* __restrict__ biascat)
{
    int i = blockIdx.x * blockDim.x + threadIdx.x;
    if (i < 4194304) {
        float4 v = reinterpret_cast<const float4*>(x)[i];
        short4 o;
        o.x = f2bf(v.x); o.y = f2bf(v.y); o.z = f2bf(v.z); o.w = f2bf(v.w);
        reinterpret_cast<short4*>(x_bf)[i] = o;
    } else if (i < 5242880) {
        int j = i - 4194304;
        int seg = j >> 18, off = j & ((1 << 18) - 1);
        const float* s = (seg == 0) ? W_ln_z : (seg == 1) ? W_dt : (seg == 2) ? W_g : W_y;
        float4 v = reinterpret_cast<const float4*>(s)[off];
        short4 o;
        o.x = f2bf(v.x); o.y = f2bf(v.y); o.z = f2bf(v.z); o.w = f2bf(v.w);
        reinterpret_cast<short4*>(Wcat)[j] = o;
    } else if (i < 5243648) {
        int j = i - 5242880;
        int seg = j >> 8, off = j & 255;
        const float* s = (seg == 0) ? b_ln_z : (seg == 1) ? b_dt : b_g;
        reinterpret_cast<float4*>(biascat)[j] =
            reinterpret_cast<const float4*>(s)[off];
    }
}

// ================= 128x128 bf16 GEMM, 8 waves, 2 blocks/CU ===========
// waves: wm=wid>>2 (M half, 64 rows), wn=wid&3 (32-col slice). Per-wave out 64x32.
// LDS: As[2bufs][2halves][64x64], Bs same -> 64KB/block. BK=64, 2 K-tiles/iter,
// 8 phases (4 MFMA each), 1 stage-load/phase, VM2 fences at P4/P8 (r9 pattern).

// stage one 64-row half (1 load/thread): arrh = &As0[half][0]
#define STG(arrh, gbase, half, kofs)                                               \
  do {                                                                             \
    int _row = tid >> 3, _g = tid & 7;                                             \
    int _gsw = _g ^ (_row & 7);                                                    \
    __builtin_amdgcn_global_load_lds(                                              \
      (const __attribute__((address_space(1))) void*)(                             \
          (gbase) + (size_t)((half) * 64 + _row) * K + (kofs) + _gsw * 8),         \
      (__attribute__((address_space(3))) void*)(&(arrh)[wid * 512]),               \
      16, 0, 0);                                                                   \
  } while (0)

// read 4 A m-frags (both kk) from the wave's own half
#define LDA(dst, buf)                                                              \
  _Pragma("unroll")                                                                \
  for (int _m = 0; _m < 4; ++_m) {                                                 \
    int _r = _m * 16 + lrow;                                                       \
    _Pragma("unroll")                                                              \
    for (int _kk = 0; _kk < 2; ++_kk)                                              \
      dst[_m][_kk] = *(const short8v*)&buf[wm][_r * 64 +                           \
                       (((_kk * 4 + kq) ^ (_r & 7)) * 8)];                         \
  }

// read 1 B n-frag (both kk) from the wave's own half
#define LDB(dst, buf, ni)                                                          \
  {                                                                                \
    int _c = (wn & 1) * 32 + (ni) * 16 + lrow;                                     \
    _Pragma("unroll")                                                              \
    for (int _kk = 0; _kk < 2; ++_kk)                                              \
      dst[_kk] = *(const short8v*)&buf[wn >> 1][_c * 64 +                          \
                   (((_kk * 4 + kq) ^ (_c & 7)) * 8)];                             \
  }

// 4 MFMA: m in {mi0, mi0+1} x n=ni x kk
#define MFMAP(mi0, ni, bfr)                                                        \
  __builtin_amdgcn_s_setprio(1);                                                   \
  _Pragma("unroll")                                                                \
  for (int _kk = 0; _kk < 2; ++_kk)                                                \
    _Pragma("unroll")                                                              \
    for (int _m = (mi0); _m < (mi0) + 2; ++_m)                                     \
      acc[_m][ni] = __builtin_amdgcn_mfma_f32_16x16x32_bf16(                       \
          af[_m][_kk], bfr[_kk], acc[_m][ni], 0, 0, 0);                            \
  __builtin_amdgcn_s_setprio(0);

#define BARB()   __builtin_amdgcn_s_barrier()
#define VM2()    asm volatile("s_waitcnt vmcnt(2)")
#define VM0()    asm volatile("s_waitcnt vmcnt(0)")

template<int OUT_BF16, int HAS_GATE>
__global__ __launch_bounds__(512, 4) void gemm128(
    const short* __restrict__ A, const short* __restrict__ Bm,
    const float* __restrict__ bias, void* __restrict__ Cv,
    int M, int N, int K,
    const short* __restrict__ gate, int ldg)
{
    __shared__ short As0[2][4096], As1[2][4096];   // [half][64x64], 8KB per half
    __shared__ short Bs0[2][4096], Bs1[2][4096];

    const int tid  = threadIdx.x;
    const int lane = tid & 63;
    const int wid  = tid >> 6;          // 0..7
    const int wm   = wid >> 2;          // 0..1 (A half)
    const int wn   = wid & 3;           // 0..3 (32-col slice; B half = wn>>1)
    const int lrow = lane & 15;
    const int kq   = lane >> 4;

    const int gx  = gridDim.x;
    const int nwg = gx * gridDim.y;
    int flat = blockIdx.y * gx + blockIdx.x;
    if ((nwg & 7) == 0) { int q = nwg >> 3; flat = (flat & 7) * q + (flat >> 3); }
    const int m0 = (flat / gx) * 128;
    const int n0 = (flat % gx) * 128;

    const short* Abase = A + (size_t)m0 * K;
    const short* Bbase = Bm + (size_t)n0 * K;

    f32x4 acc[4][2];
#pragma unroll
    for (int i = 0; i < 4; ++i)
#pragma unroll
        for (int j = 0; j < 2; ++j)
            acc[i][j] = (f32x4){0.f, 0.f, 0.f, 0.f};

    short8v af[4][2], b0[2], b1[2];

    // prologue: tile0 (4 halves) + tile1 h0 of A,B; land tile0 (VM2 -> 2 in flight)
    STG(As0[0], Abase, 0, 0);
    STG(As0[1], Abase, 1, 0);
    STG(Bs0[0], Bbase, 0, 0);
    STG(Bs0[1], Bbase, 1, 0);
    STG(As1[0], Abase, 0, 64);
    STG(Bs1[0], Bbase, 0, 64);
    VM2(); BARB();

    const int NT = K / 64;              // even, >= 4
    for (int t = 0; t < NT; t += 2) {
        const int k1 = (t + 1) * 64, k2 = (t + 2) * 64, k3 = (t + 3) * 64;
        const bool more = (t + 2) < NT;

        // ---- K-tile 0 (buf0) ----
        LDA(af, As0) LDB(b0, Bs0, 0)
        STG(As1[1], Abase, 1, k1);
        BARB(); MFMAP(0, 0, b0)                           // P1
        LDB(b1, Bs0, 1)
        STG(Bs1[1], Bbase, 1, k1);
        BARB(); MFMAP(2, 0, b0)                           // P2
        if (more) STG(As0[0], Abase, 0, k2);
        BARB(); MFMAP(2, 1, b1)                           // P3
        if (more) { STG(Bs0[0], Bbase, 0, k2); VM2(); } else { VM0(); }
        BARB(); MFMAP(0, 1, b1)                           // P4

        // ---- K-tile 1 (buf1) ----
        LDA(af, As1) LDB(b0, Bs1, 0)
        if (more) STG(As0[1], Abase, 1, k2);
        BARB(); MFMAP(0, 0, b0)                           // P5
        LDB(b1, Bs1, 1)
        if (more) STG(Bs0[1], Bbase, 1, k2);
        BARB(); MFMAP(2, 0, b0)                           // P6
        if (more) STG(As1[0], Abase, 0, k3);
        BARB(); MFMAP(2, 1, b1)                           // P7
        if (more) { STG(Bs1[0], Bbase, 0, k3); VM2(); }
        BARB(); MFMAP(0, 1, b1)                           // P8
    }

    // epilogue: C/D layout col=lane&15, row=(lane>>4)*4+reg
    const int lr4 = (lane >> 4) * 4;
#pragma unroll
    for (int mi = 0; mi < 4; ++mi) {
        int rowb = m0 + wm * 64 + mi * 16 + lr4;
#pragma unroll
        for (int ni = 0; ni < 2; ++ni) {
            int col = n0 + wn * 32 + ni * 16 + lrow;
            float bv = bias[col];
#pragma unroll
            for (int r = 0; r < 4; ++r) {
                int row = rowb + r;
                float val = acc[mi][ni][r] + bv;
                if (HAS_GATE) {
                    float g = bf2f(gate[(size_t)row * ldg + col]);
                    val *= g * sigf(g);
                }
                if (OUT_BF16)
                    ((short*)Cv)[(size_t)row * N + col] = f2bf(val);
                else
                    ((float*)Cv)[(size_t)row * N + col] = val;
            }
        }
    }
}

// ---------------- scan pass 1: 8-deep prefetch groups, grid (64,4,2) x 256 thr ----------------
__global__ __launch_bounds__(256) void chunk_reduce(
    const short* __restrict__ pre, float* __restrict__ sA, float* __restrict__ sBv)
{
    const int t = threadIdx.x;
    const int c = blockIdx.x;
    const int b = blockIdx.y;
    const int d0 = blockIdx.z * 512 + 2 * t;
    float A0 = 1.f, A1 = 1.f, B0 = 0.f, B1 = 0.f;
    size_t base = ((size_t)(b * LDIM) + c * LCHUNK) * NPROJ + d0;
    for (int i = 0; i < LCHUNK; i += 8) {
        uint z[8], dv[8];
#pragma unroll
        for (int k = 0; k < 8; ++k) {
            z[k]  = *(const uint*)&pre[base + (size_t)k * NPROJ];
            dv[k] = *(const uint*)&pre[base + (size_t)k * NPROJ + DDIM];
        }
#pragma unroll
        for (int k = 0; k < 8; ++k) {
            SCANSTEP(z[k], dv[k], B0, B1, A0, A1, 1)
        }
        base += 8 * NPROJ;
    }
    int idx = ((b * NCHUNK + c) << 10) + d0;
    *reinterpret_cast<float2*>(&sA[idx])  = make_float2(A0, A1);
    *reinterpret_cast<float2*>(&sBv[idx]) = make_float2(B0, B1);
}

// ---------------- scan pass 2: prefix over chunks, 4-deep prefetch ----------------
__global__ __launch_bounds__(1024) void chunk_prefix(
    const float* __restrict__ sA, const float* __restrict__ sBv,
    const float* __restrict__ hidden, float* __restrict__ sI)
{
    const int d = threadIdx.x;
    const int b = blockIdx.x;
    float h = hidden[b * DDIM + d];
    int idx = (b * NCHUNK << 10) + d;
    for (int c = 0; c < NCHUNK; c += 4) {
        float a0 = sA[idx];            float v0 = sBv[idx];
        float a1 = sA[idx + 1024];     float v1 = sBv[idx + 1024];
        float a2 = sA[idx + 2048];     float v2 = sBv[idx + 2048];
        float a3 = sA[idx + 3072];     float v3 = sBv[idx + 3072];
        sI[idx]        = h; h = v0 + a0 * h;
        sI[idx + 1024] = h; h = v1 + a1 * h;
        sI[idx + 2048] = h; h = v2 + a2 * h;
        sI[idx + 3072] = h; h = v3 + a3 * h;
        idx += 4096;
    }
}

// ---------------- scan pass 3: 8-deep prefetch, grid (64,4,2) x 256 thr ----------------
__global__ __launch_bounds__(256) void chunk_apply(
    const short* __restrict__ pre, const float* __restrict__ sI,
    float* __restrict__ hout, short* __restrict__ hbf)
{
    const int t = threadIdx.x;
    const int c = blockIdx.x;
    const int b = blockIdx.y;
    const int d0 = blockIdx.z * 512 + 2 * t;
    float2 hi = *reinterpret_cast<const float2*>(&sI[((b * NCHUNK + c) << 10) + d0]);
    float h0 = hi.x, h1 = hi.y;
    size_t base  = ((size_t)(b * LDIM) + c * LCHUNK) * NPROJ + d0;
    size_t obase = ((size_t)(b * LDIM) + c * LCHUNK) * DDIM + d0;
    for (int i = 0; i < LCHUNK; i += 8) {
        uint z[8], dv[8];
#pragma unroll
        for (int k = 0; k < 8; ++k) {
            z[k]  = *(const uint*)&pre[base + (size_t)k * NPROJ];
            dv[k] = *(const uint*)&pre[base + (size_t)k * NPROJ + DDIM];
        }
        float dummyA = 0.f, dummyB = 0.f;
#pragma unroll
        for (int k = 0; k < 8; ++k) {
            SCANSTEP(z[k], dv[k], h0, h1, dummyA, dummyB, 0)
            *reinterpret_cast<float2*>(&hout[obase + (size_t)k * DDIM]) =
                make_float2(h0, h1);
            *reinterpret_cast<uint*>(&hbf[obase + (size_t)k * DDIM]) =
                ((uint)(unsigned short)f2bf(h0)) |
                (((uint)(unsigned short)f2bf(h1)) << 16);
        }
        base += 8 * NPROJ;
        obase += 8 * DDIM;
    }
}

extern "C" void kernel_launch(void* const* d_in, const int* in_sizes, int n_in,
                              void* d_out, int out_size, void* d_ws, size_t ws_size,
                              hipStream_t stream) {
    const float* x      = (const float*)d_in[0];
    const float* hidden = (const float*)d_in[1];
    const float* W_ln_z = (const float*)d_in[2];
    const float* b_ln_z = (const float*)d_in[3];
    const float* W_dt   = (const float*)d_in[4];
    const float* b_dt   = (const float*)d_in[5];
    const float* W_y    = (const float*)d_in[6];
    const float* b_y    = (const float*)d_in[7];
    const float* W_g    = (const float*)d_in[8];
    const float* b_g    = (const float*)d_in[9];

    char* ws = (char*)d_ws;
    short* x_bf   = (short*)(ws + 0);                       // 33,554,432 (reused as h_bf)
    short* Wcat   = (short*)(ws + 33554432);                //  6,291,456
    short* Wy_bf  = (short*)(ws + 39845888);                //  2,097,152 (contiguous after Wcat)
    float* biascat= (float*)(ws + 41943040);                //     12,288
    short* pre    = (short*)(ws + 41955328);                // 100,663,296
    float* sA     = (float*)(ws + 142618624);               //  1,048,576
    float* sBv    = (float*)(ws + 143667200);               //  1,048,576
    float* sI     = (float*)(ws + 144715776);               //  1,048,576

    fused_init<<<20484, 256, 0, stream>>>(x, W_ln_z, W_dt, W_g, W_y,
                                          b_ln_z, b_dt, b_g, x_bf, Wcat, biascat);

    gemm128<1, 0><<<dim3(NPROJ / 128, MROWS / 128), 512, 0, stream>>>(
        x_bf, Wcat, biascat, pre, MROWS, NPROJ, KDIM, nullptr, 0);

    float* y_out = (float*)d_out;
    float* h_out = (float*)d_out + (size_t)MROWS * DDIM;
    short* h_bf  = x_bf;
    chunk_reduce<<<dim3(NCHUNK, BDIM, 2), 256, 0, stream>>>(pre, sA, sBv);
    chunk_prefix<<<dim3(BDIM), 1024, 0, stream>>>(sA, sBv, hidden, sI);
    chunk_apply<<<dim3(NCHUNK, BDIM, 2), 256, 0, stream>>>(pre, sI, h_out, h_bf);

    gemm128<0, 1><<<dim3(DDIM / 128, MROWS / 128), 512, 0, stream>>>(
        h_bf, Wy_bf, b_y, y_out, MROWS, DDIM, KDIM, pre + 2 * DDIM, NPROJ);
}

// Round 16
// 237.165 us; speedup vs baseline: 1.0795x; 1.0795x over previous
//
#include <hip/hip_runtime.h>

// SioConvPS: fused init -> z/dt/g projections (bf16 MFMA GEMM, 256^2, r9
// schedule) -> stable linear scan (reduce + apply-with-inline-prefix, 8-deep
// prefetch) -> gated y GEMM.  5 dispatches total.
// Outputs (f32): d_out = [y (B,L,D), h (B,L,D)].

#define BDIM 4
#define LDIM 4096
#define DDIM 1024
#define MROWS (BDIM * LDIM)   // 16384
#define KDIM 1024
#define NPROJ 3072
#define NCHUNK 64             // chunks along L
#define LCHUNK 64             // LDIM / NCHUNK

typedef __attribute__((ext_vector_type(8))) short short8v;
typedef __attribute__((ext_vector_type(4))) float f32x4;
typedef unsigned int uint;

__device__ __forceinline__ float bf2f(short u) {
    union { float f; uint i; } v;
    v.i = ((uint)(unsigned short)u) << 16;
    return v.f;
}
__device__ __forceinline__ short f2bf(float f) {
    union { float f; uint i; } v; v.f = f;
    uint r = v.i + 0x7FFFu + ((v.i >> 16) & 1u);  // RNE
    return (short)(r >> 16);
}
__device__ __forceinline__ float sigf(float x) { return 1.f / (1.f + __expf(-x)); }

#define SCANSTEP(zz, dd, H0, H1, A0, A1, DO_A)                                     \
  {                                                                                \
    float _z0 = bf2f((short)((zz) & 0xffff)), _z1 = bf2f((short)((zz) >> 16));     \
    float _d0 = bf2f((short)((dd) & 0xffff)), _d1 = bf2f((short)((dd) >> 16));     \
    float _e0 = __expf(-_d0), _r0 = 1.f / (1.f + _e0);                             \
    float _o0 = _e0 * _r0, _q0 = sigf(_z0) * _r0;                                  \
    float _e1 = __expf(-_d1), _r1 = 1.f / (1.f + _e1);                             \
    float _o1 = _e1 * _r1, _q1 = sigf(_z1) * _r1;                                  \
    H0 = _q0 + _o0 * H0; H1 = _q1 + _o1 * H1;                                      \
    if (DO_A) { A0 *= _o0; A1 *= _o1; }                                            \
  }

// ---------------- fused init: x cast + 4 weight casts + bias concat ----------------
__global__ __launch_bounds__(256) void fused_init(
    const float* __restrict__ x,
    const float* __restrict__ W_ln_z, const float* __restrict__ W_dt,
    const float* __restrict__ W_g,    const float* __restrict__ W_y,
    const float* __restrict__ b_ln_z, const float* __restrict__ b_dt,
    const float* __restrict__ b_g,
    short* __restrict__ x_bf, short* __restrict__ Wcat, float* __restrict__ biascat)
{
    int i = blockIdx.x * blockDim.x + threadIdx.x;
    if (i < 4194304) {
        float4 v = reinterpret_cast<const float4*>(x)[i];
        short4 o;
        o.x = f2bf(v.x); o.y = f2bf(v.y); o.z = f2bf(v.z); o.w = f2bf(v.w);
        reinterpret_cast<short4*>(x_bf)[i] = o;
    } else if (i < 5242880) {
        int j = i - 4194304;
        int seg = j >> 18, off = j & ((1 << 18) - 1);
        const float* s = (seg == 0) ? W_ln_z : (seg == 1) ? W_dt : (seg == 2) ? W_g : W_y;
        float4 v = reinterpret_cast<const float4*>(s)[off];
        short4 o;
        o.x = f2bf(v.x); o.y = f2bf(v.y); o.z = f2bf(v.z); o.w = f2bf(v.w);
        reinterpret_cast<short4*>(Wcat)[j] = o;
    } else if (i < 5243648) {
        int j = i - 5242880;
        int seg = j >> 8, off = j & 255;
        const float* s = (seg == 0) ? b_ln_z : (seg == 1) ? b_dt : b_g;
        reinterpret_cast<float4*>(biascat)[j] =
            reinterpret_cast<const float4*>(s)[off];
    }
}

// ================= 256x256 bf16 GEMM (r9 schedule, best measured: 832 TF) ===========
#define STAGE(arr, gbase, half, kofs)                                              \
  do {                                                                             \
    _Pragma("unroll")                                                              \
    for (int _i = 0; _i < 2; ++_i) {                                               \
      int _c = _i * 512 + tid;                                                     \
      int _row = _c >> 3, _g = _c & 7;                                             \
      int _gsw = _g ^ (_row & 7);                                                  \
      __builtin_amdgcn_global_load_lds(                                            \
        (const __attribute__((address_space(1))) void*)(                           \
            (gbase) + (size_t)((half) * 128 + _row) * K + (kofs) + _gsw * 8),      \
        (__attribute__((address_space(3))) void*)(                                 \
            &arr[(_i * 512 + wid * 64) * 8]),                                      \
        16, 0, 0);                                                                 \
    }                                                                              \
  } while (0)

#define LDA4(dst, arr)                                                             \
  _Pragma("unroll")                                                                \
  for (int _m = 0; _m < 4; ++_m) {                                                 \
    int _r = _m * 32 + wm * 16 + lrow;                                             \
    _Pragma("unroll")                                                              \
    for (int _kk = 0; _kk < 2; ++_kk)                                              \
      dst[_m][_kk] = *(const short8v*)&arr[_r * 64 +                               \
                       (((_kk * 4 + kq) ^ (lrow & 7)) * 8)];                       \
  }

#define LDB2(dst, arr)                                                             \
  _Pragma("unroll")                                                                \
  for (int _n = 0; _n < 2; ++_n) {                                                 \
    int _r = _n * 64 + wn * 16 + lrow;                                             \
    _Pragma("unroll")                                                              \
    for (int _kk = 0; _kk < 2; ++_kk)                                              \
      dst[_n][_kk] = *(const short8v*)&arr[_r * 64 +                               \
                       (((_kk * 4 + kq) ^ (lrow & 7)) * 8)];                       \
  }

#define MFMAQ(mi0, ni0, afr, bfr)                                                  \
  __builtin_amdgcn_s_setprio(1);                                                   \
  _Pragma("unroll")                                                                \
  for (int _kk = 0; _kk < 2; ++_kk)                                                \
    _Pragma("unroll")                                                              \
    for (int _m = 0; _m < 4; ++_m)                                                 \
      _Pragma("unroll")                                                            \
      for (int _n = 0; _n < 2; ++_n)                                               \
        acc[(mi0) + _m][(ni0) + _n] = __builtin_amdgcn_mfma_f32_16x16x32_bf16(     \
            afr[_m][_kk], bfr[_n][_kk], acc[(mi0) + _m][(ni0) + _n], 0, 0, 0);     \
  __builtin_amdgcn_s_setprio(0);

#define BARB()   __builtin_amdgcn_s_barrier()
#define VM4()    asm volatile("s_waitcnt vmcnt(4)")
#define VM0()    asm volatile("s_waitcnt vmcnt(0)")

template<int OUT_BF16, int HAS_GATE>
__global__ __launch_bounds__(512, 2) void gemm256(
    const short* __restrict__ A, const short* __restrict__ Bm,
    const float* __restrict__ bias, void* __restrict__ Cv,
    int M, int N, int K,
    const short* __restrict__ gate, int ldg)
{
    __shared__ short As0h0[8192], As0h1[8192], As1h0[8192], As1h1[8192];
    __shared__ short Bs0h0[8192], Bs0h1[8192], Bs1h0[8192], Bs1h1[8192];

    const int tid  = threadIdx.x;
    const int lane = tid & 63;
    const int wid  = tid >> 6;
    const int wm   = wid >> 2;
    const int wn   = wid & 3;
    const int lrow = lane & 15;
    const int kq   = lane >> 4;

    const int gx  = gridDim.x;
    const int nwg = gx * gridDim.y;
    int flat = blockIdx.y * gx + blockIdx.x;
    if ((nwg & 7) == 0) { int q = nwg >> 3; flat = (flat & 7) * q + (flat >> 3); }
    const int m0 = (flat / gx) * 256;
    const int n0 = (flat % gx) * 256;

    const short* Abase = A + (size_t)m0 * K;
    const short* Bbase = Bm + (size_t)n0 * K;

    f32x4 acc[8][4];
#pragma unroll
    for (int i = 0; i < 8; ++i)
#pragma unroll
        for (int j = 0; j < 4; ++j)
            acc[i][j] = (f32x4){0.f, 0.f, 0.f, 0.f};

    STAGE(As0h0, Abase, 0, 0);
    STAGE(As0h1, Abase, 1, 0);
    STAGE(Bs0h0, Bbase, 0, 0);
    STAGE(Bs0h1, Bbase, 1, 0);
    STAGE(As1h0, Abase, 0, 64);
    STAGE(Bs1h0, Bbase, 0, 64);
    VM4(); BARB();

    const int NT = K / 64;
    for (int t = 0; t < NT; t += 2) {
        const int k1 = (t + 1) * 64, k2 = (t + 2) * 64, k3 = (t + 3) * 64;
        const bool more = (t + 2) < NT;
        short8v af[4][2], b0[2][2], b1[2][2];

        LDA4(af, As0h0) LDB2(b0, Bs0h0)
        STAGE(As1h1, Abase, 1, k1);
        BARB(); MFMAQ(0, 0, af, b0)                       // P1

        LDB2(b1, Bs0h1)
        STAGE(Bs1h1, Bbase, 1, k1);
        BARB(); MFMAQ(0, 2, af, b1)                       // P2

        LDA4(af, As0h1)
        if (more) STAGE(As0h0, Abase, 0, k2);
        BARB(); MFMAQ(4, 2, af, b1)                       // P3

        if (more) { STAGE(Bs0h0, Bbase, 0, k2); VM4(); } else { VM0(); }
        BARB(); MFMAQ(4, 0, af, b0)                       // P4

        LDA4(af, As1h0) LDB2(b0, Bs1h0)
        if (more) STAGE(As0h1, Abase, 1, k2);
        BARB(); MFMAQ(0, 0, af, b0)                       // P5

        LDB2(b1, Bs1h1)
        if (more) STAGE(Bs0h1, Bbase, 1, k2);
        BARB(); MFMAQ(0, 2, af, b1)                       // P6

        LDA4(af, As1h1)
        if (more) STAGE(As1h0, Abase, 0, k3);
        BARB(); MFMAQ(4, 2, af, b1)                       // P7

        if (more) { STAGE(Bs1h0, Bbase, 0, k3); VM4(); }
        BARB(); MFMAQ(4, 0, af, b0)                       // P8
    }

    const int lr4 = (lane >> 4) * 4;
#pragma unroll
    for (int mi = 0; mi < 8; ++mi) {
        int rowb = m0 + mi * 32 + wm * 16 + lr4;
#pragma unroll
        for (int ni = 0; ni < 4; ++ni) {
            int col = n0 + ni * 64 + wn * 16 + lrow;
            float bv = bias[col];
#pragma unroll
            for (int r = 0; r < 4; ++r) {
                int row = rowb + r;
                float val = acc[mi][ni][r] + bv;
                if (HAS_GATE) {
                    float g = bf2f(gate[(size_t)row * ldg + col]);
                    val *= g * sigf(g);
                }
                if (OUT_BF16)
                    ((short*)Cv)[(size_t)row * N + col] = f2bf(val);
                else
                    ((float*)Cv)[(size_t)row * N + col] = val;
            }
        }
    }
}

// ---------------- scan pass 1: 8-deep prefetch groups, grid (64,4,2) x 256 thr ----------------
__global__ __launch_bounds__(256) void chunk_reduce(
    const short* __restrict__ pre, float* __restrict__ sA, float* __restrict__ sBv)
{
    const int t = threadIdx.x;
    const int c = blockIdx.x;
    const int b = blockIdx.y;
    const int d0 = blockIdx.z * 512 + 2 * t;
    float A0 = 1.f, A1 = 1.f, B0 = 0.f, B1 = 0.f;
    size_t base = ((size_t)(b * LDIM) + c * LCHUNK) * NPROJ + d0;
    for (int i = 0; i < LCHUNK; i += 8) {
        uint z[8], dv[8];
#pragma unroll
        for (int k = 0; k < 8; ++k) {
            z[k]  = *(const uint*)&pre[base + (size_t)k * NPROJ];
            dv[k] = *(const uint*)&pre[base + (size_t)k * NPROJ + DDIM];
        }
#pragma unroll
        for (int k = 0; k < 8; ++k) {
            SCANSTEP(z[k], dv[k], B0, B1, A0, A1, 1)
        }
        base += 8 * NPROJ;
    }
    int idx = ((b * NCHUNK + c) << 10) + d0;
    *reinterpret_cast<float2*>(&sA[idx])  = make_float2(A0, A1);
    *reinterpret_cast<float2*>(&sBv[idx]) = make_float2(B0, B1);
}

// ------- scan pass 2 (fused prefix+apply): fold chunk summaries 0..c-1, then scan -------
__global__ __launch_bounds__(256) void chunk_apply(
    const short* __restrict__ pre, const float* __restrict__ sA,
    const float* __restrict__ sBv, const float* __restrict__ hidden,
    float* __restrict__ hout, short* __restrict__ hbf)
{
    const int t = threadIdx.x;
    const int c = blockIdx.x;
    const int b = blockIdx.y;
    const int d0 = blockIdx.z * 512 + 2 * t;

    // inline prefix: h_init = fold_{k<c} (Bv_k + A_k * h), from hidden.
    // loads are independent (only the FMA chain is serial) -> 8-deep batches.
    float2 hv = *reinterpret_cast<const float2*>(&hidden[b * DDIM + d0]);
    float h0 = hv.x, h1 = hv.y;
    {
        int base_idx = (b * NCHUNK << 10) + d0;
        int k = 0;
        for (; k + 8 <= c; k += 8) {
            float2 a[8], v[8];
#pragma unroll
            for (int j = 0; j < 8; ++j) {
                int idx = base_idx + ((k + j) << 10);
                a[j] = *reinterpret_cast<const float2*>(&sA[idx]);
                v[j] = *reinterpret_cast<const float2*>(&sBv[idx]);
            }
#pragma unroll
            for (int j = 0; j < 8; ++j) {
                h0 = v[j].x + a[j].x * h0;
                h1 = v[j].y + a[j].y * h1;
            }
        }
        for (; k < c; ++k) {
            int idx = base_idx + (k << 10);
            float2 a = *reinterpret_cast<const float2*>(&sA[idx]);
            float2 v = *reinterpret_cast<const float2*>(&sBv[idx]);
            h0 = v.x + a.x * h0;
            h1 = v.y + a.y * h1;
        }
    }

    size_t base  = ((size_t)(b * LDIM) + c * LCHUNK) * NPROJ + d0;
    size_t obase = ((size_t)(b * LDIM) + c * LCHUNK) * DDIM + d0;
    for (int i = 0; i < LCHUNK; i += 8) {
        uint z[8], dv[8];
#pragma unroll
        for (int k = 0; k < 8; ++k) {
            z[k]  = *(const uint*)&pre[base + (size_t)k * NPROJ];
            dv[k] = *(const uint*)&pre[base + (size_t)k * NPROJ + DDIM];
        }
        float dummyA = 0.f, dummyB = 0.f;
#pragma unroll
        for (int k = 0; k < 8; ++k) {
            SCANSTEP(z[k], dv[k], h0, h1, dummyA, dummyB, 0)
            *reinterpret_cast<float2*>(&hout[obase + (size_t)k * DDIM]) =
                make_float2(h0, h1);
            *reinterpret_cast<uint*>(&hbf[obase + (size_t)k * DDIM]) =
                ((uint)(unsigned short)f2bf(h0)) |
                (((uint)(unsigned short)f2bf(h1)) << 16);
        }
        base += 8 * NPROJ;
        obase += 8 * DDIM;
    }
}

extern "C" void kernel_launch(void* const* d_in, const int* in_sizes, int n_in,
                              void* d_out, int out_size, void* d_ws, size_t ws_size,
                              hipStream_t stream) {
    const float* x      = (const float*)d_in[0];
    const float* hidden = (const float*)d_in[1];
    const float* W_ln_z = (const float*)d_in[2];
    const float* b_ln_z = (const float*)d_in[3];
    const float* W_dt   = (const float*)d_in[4];
    const float* b_dt   = (const float*)d_in[5];
    const float* W_y    = (const float*)d_in[6];
    const float* b_y    = (const float*)d_in[7];
    const float* W_g    = (const float*)d_in[8];
    const float* b_g    = (const float*)d_in[9];

    char* ws = (char*)d_ws;
    short* x_bf   = (short*)(ws + 0);                       // 33,554,432 (reused as h_bf)
    short* Wcat   = (short*)(ws + 33554432);                //  6,291,456
    short* Wy_bf  = (short*)(ws + 39845888);                //  2,097,152 (contiguous after Wcat)
    float* biascat= (float*)(ws + 41943040);                //     12,288
    short* pre    = (short*)(ws + 41955328);                // 100,663,296
    float* sA     = (float*)(ws + 142618624);               //  1,048,576
    float* sBv    = (float*)(ws + 143667200);               //  1,048,576

    fused_init<<<20484, 256, 0, stream>>>(x, W_ln_z, W_dt, W_g, W_y,
                                          b_ln_z, b_dt, b_g, x_bf, Wcat, biascat);

    gemm256<1, 0><<<dim3(NPROJ / 256, MROWS / 256), 512, 0, stream>>>(
        x_bf, Wcat, biascat, pre, MROWS, NPROJ, KDIM, nullptr, 0);

    float* y_out = (float*)d_out;
    float* h_out = (float*)d_out + (size_t)MROWS * DDIM;
    short* h_bf  = x_bf;
    chunk_reduce<<<dim3(NCHUNK, BDIM, 2), 256, 0, stream>>>(pre, sA, sBv);
    chunk_apply<<<dim3(NCHUNK, BDIM, 2), 256, 0, stream>>>(pre, sA, sBv, hidden,
                                                           h_out, h_bf);

    gemm256<0, 1><<<dim3(DDIM / 256, MROWS / 256), 512, 0, stream>>>(
        h_bf, Wy_bf, b_y, y_out, MROWS, DDIM, KDIM, pre + 2 * DDIM, NPROJ);
}

// Round 17
// 234.030 us; speedup vs baseline: 1.0940x; 1.0134x over previous
//
#include <hip/hip_runtime.h>

// SioConvPS: fused init -> z/dt/g projections (bf16 MFMA GEMM, 256^2, r9
// schedule + sched_barrier(0) pinning reads BEFORE each phase barrier so their
// LDS drain overlaps other waves' previous-phase MFMA) -> stable linear scan
// (reduce + apply-with-inline-prefix) -> gated y GEMM.  5 dispatches.
// Outputs (f32): d_out = [y (B,L,D), h (B,L,D)].

#define BDIM 4
#define LDIM 4096
#define DDIM 1024
#define MROWS (BDIM * LDIM)   // 16384
#define KDIM 1024
#define NPROJ 3072
#define NCHUNK 64             // chunks along L
#define LCHUNK 64             // LDIM / NCHUNK

typedef __attribute__((ext_vector_type(8))) short short8v;
typedef __attribute__((ext_vector_type(4))) float f32x4;
typedef unsigned int uint;

__device__ __forceinline__ float bf2f(short u) {
    union { float f; uint i; } v;
    v.i = ((uint)(unsigned short)u) << 16;
    return v.f;
}
__device__ __forceinline__ short f2bf(float f) {
    union { float f; uint i; } v; v.f = f;
    uint r = v.i + 0x7FFFu + ((v.i >> 16) & 1u);  // RNE
    return (short)(r >> 16);
}
__device__ __forceinline__ float sigf(float x) { return 1.f / (1.f + __expf(-x)); }

#define SCANSTEP(zz, dd, H0, H1, A0, A1, DO_A)                                     \
  {                                                                                \
    float _z0 = bf2f((short)((zz) & 0xffff)), _z1 = bf2f((short)((zz) >> 16));     \
    float _d0 = bf2f((short)((dd) & 0xffff)), _d1 = bf2f((short)((dd) >> 16));     \
    float _e0 = __expf(-_d0), _r0 = 1.f / (1.f + _e0);                             \
    float _o0 = _e0 * _r0, _q0 = sigf(_z0) * _r0;                                  \
    float _e1 = __expf(-_d1), _r1 = 1.f / (1.f + _e1);                             \
    float _o1 = _e1 * _r1, _q1 = sigf(_z1) * _r1;                                  \
    H0 = _q0 + _o0 * H0; H1 = _q1 + _o1 * H1;                                      \
    if (DO_A) { A0 *= _o0; A1 *= _o1; }                                            \
  }

// ---------------- fused init: x cast + 4 weight casts + bias concat ----------------
__global__ __launch_bounds__(256) void fused_init(
    const float* __restrict__ x,
    const float* __restrict__ W_ln_z, const float* __restrict__ W_dt,
    const float* __restrict__ W_g,    const float* __restrict__ W_y,
    const float* __restrict__ b_ln_z, const float* __restrict__ b_dt,
    const float* __restrict__ b_g,
    short* __restrict__ x_bf, short* __restrict__ Wcat, float* __restrict__ biascat)
{
    int i = blockIdx.x * blockDim.x + threadIdx.x;
    if (i < 4194304) {
        float4 v = reinterpret_cast<const float4*>(x)[i];
        short4 o;
        o.x = f2bf(v.x); o.y = f2bf(v.y); o.z = f2bf(v.z); o.w = f2bf(v.w);
        reinterpret_cast<short4*>(x_bf)[i] = o;
    } else if (i < 5242880) {
        int j = i - 4194304;
        int seg = j >> 18, off = j & ((1 << 18) - 1);
        const float* s = (seg == 0) ? W_ln_z : (seg == 1) ? W_dt : (seg == 2) ? W_g : W_y;
        float4 v = reinterpret_cast<const float4*>(s)[off];
        short4 o;
        o.x = f2bf(v.x); o.y = f2bf(v.y); o.z = f2bf(v.z); o.w = f2bf(v.w);
        reinterpret_cast<short4*>(Wcat)[j] = o;
    } else if (i < 5243648) {
        int j = i - 5242880;
        int seg = j >> 8, off = j & 255;
        const float* s = (seg == 0) ? b_ln_z : (seg == 1) ? b_dt : b_g;
        reinterpret_cast<float4*>(biascat)[j] =
            reinterpret_cast<const float4*>(s)[off];
    }
}

// ================= 256x256 bf16 GEMM (r9 schedule + pre-barrier read pinning) ===========
#define STAGE(arr, gbase, half, kofs)                                              \
  do {                                                                             \
    _Pragma("unroll")                                                              \
    for (int _i = 0; _i < 2; ++_i) {                                               \
      int _c = _i * 512 + tid;                                                     \
      int _row = _c >> 3, _g = _c & 7;                                             \
      int _gsw = _g ^ (_row & 7);                                                  \
      __builtin_amdgcn_global_load_lds(                                            \
        (const __attribute__((address_space(1))) void*)(                           \
            (gbase) + (size_t)((half) * 128 + _row) * K + (kofs) + _gsw * 8),      \
        (__attribute__((address_space(3))) void*)(                                 \
            &arr[(_i * 512 + wid * 64) * 8]),                                      \
        16, 0, 0);                                                                 \
    }                                                                              \
  } while (0)

#define LDA4(dst, arr)                                                             \
  _Pragma("unroll")                                                                \
  for (int _m = 0; _m < 4; ++_m) {                                                 \
    int _r = _m * 32 + wm * 16 + lrow;                                             \
    _Pragma("unroll")                                                              \
    for (int _kk = 0; _kk < 2; ++_kk)                                              \
      dst[_m][_kk] = *(const short8v*)&arr[_r * 64 +                               \
                       (((_kk * 4 + kq) ^ (lrow & 7)) * 8)];                       \
  }

#define LDB2(dst, arr)                                                             \
  _Pragma("unroll")                                                                \
  for (int _n = 0; _n < 2; ++_n) {                                                 \
    int _r = _n * 64 + wn * 16 + lrow;                                             \
    _Pragma("unroll")                                                              \
    for (int _kk = 0; _kk < 2; ++_kk)                                              \
      dst[_n][_kk] = *(const short8v*)&arr[_r * 64 +                               \
                       (((_kk * 4 + kq) ^ (lrow & 7)) * 8)];                       \
  }

#define MFMAQ(mi0, ni0, afr, bfr)                                                  \
  __builtin_amdgcn_s_setprio(1);                                                   \
  _Pragma("unroll")                                                                \
  for (int _kk = 0; _kk < 2; ++_kk)                                                \
    _Pragma("unroll")                                                              \
    for (int _m = 0; _m < 4; ++_m)                                                 \
      _Pragma("unroll")                                                            \
      for (int _n = 0; _n < 2; ++_n)                                               \
        acc[(mi0) + _m][(ni0) + _n] = __builtin_amdgcn_mfma_f32_16x16x32_bf16(     \
            afr[_m][_kk], bfr[_n][_kk], acc[(mi0) + _m][(ni0) + _n], 0, 0, 0);     \
  __builtin_amdgcn_s_setprio(0);

#define BARB()   __builtin_amdgcn_s_barrier()
#define VM4()    asm volatile("s_waitcnt vmcnt(4)")
#define VM0()    asm volatile("s_waitcnt vmcnt(0)")
#define PIN()    __builtin_amdgcn_sched_barrier(0)   // keep reads+stage ABOVE the barrier

template<int OUT_BF16, int HAS_GATE>
__global__ __launch_bounds__(512, 2) void gemm256(
    const short* __restrict__ A, const short* __restrict__ Bm,
    const float* __restrict__ bias, void* __restrict__ Cv,
    int M, int N, int K,
    const short* __restrict__ gate, int ldg)
{
    __shared__ short As0h0[8192], As0h1[8192], As1h0[8192], As1h1[8192];
    __shared__ short Bs0h0[8192], Bs0h1[8192], Bs1h0[8192], Bs1h1[8192];

    const int tid  = threadIdx.x;
    const int lane = tid & 63;
    const int wid  = tid >> 6;
    const int wm   = wid >> 2;
    const int wn   = wid & 3;
    const int lrow = lane & 15;
    const int kq   = lane >> 4;

    const int gx  = gridDim.x;
    const int nwg = gx * gridDim.y;
    int flat = blockIdx.y * gx + blockIdx.x;
    if ((nwg & 7) == 0) { int q = nwg >> 3; flat = (flat & 7) * q + (flat >> 3); }
    const int m0 = (flat / gx) * 256;
    const int n0 = (flat % gx) * 256;

    const short* Abase = A + (size_t)m0 * K;
    const short* Bbase = Bm + (size_t)n0 * K;

    f32x4 acc[8][4];
#pragma unroll
    for (int i = 0; i < 8; ++i)
#pragma unroll
        for (int j = 0; j < 4; ++j)
            acc[i][j] = (f32x4){0.f, 0.f, 0.f, 0.f};

    STAGE(As0h0, Abase, 0, 0);
    STAGE(As0h1, Abase, 1, 0);
    STAGE(Bs0h0, Bbase, 0, 0);
    STAGE(Bs0h1, Bbase, 1, 0);
    STAGE(As1h0, Abase, 0, 64);
    STAGE(Bs1h0, Bbase, 0, 64);
    VM4(); BARB();

    const int NT = K / 64;
    for (int t = 0; t < NT; t += 2) {
        const int k1 = (t + 1) * 64, k2 = (t + 2) * 64, k3 = (t + 3) * 64;
        const bool more = (t + 2) < NT;
        short8v af[4][2], b0[2][2], b1[2][2];

        LDA4(af, As0h0) LDB2(b0, Bs0h0)
        STAGE(As1h1, Abase, 1, k1);
        PIN(); BARB(); MFMAQ(0, 0, af, b0)                // P1

        LDB2(b1, Bs0h1)
        STAGE(Bs1h1, Bbase, 1, k1);
        PIN(); BARB(); MFMAQ(0, 2, af, b1)                // P2

        LDA4(af, As0h1)
        if (more) STAGE(As0h0, Abase, 0, k2);
        PIN(); BARB(); MFMAQ(4, 2, af, b1)                // P3

        if (more) { STAGE(Bs0h0, Bbase, 0, k2); VM4(); } else { VM0(); }
        PIN(); BARB(); MFMAQ(4, 0, af, b0)                // P4

        LDA4(af, As1h0) LDB2(b0, Bs1h0)
        if (more) STAGE(As0h1, Abase, 1, k2);
        PIN(); BARB(); MFMAQ(0, 0, af, b0)                // P5

        LDB2(b1, Bs1h1)
        if (more) STAGE(Bs0h1, Bbase, 1, k2);
        PIN(); BARB(); MFMAQ(0, 2, af, b1)                // P6

        LDA4(af, As1h1)
        if (more) STAGE(As1h0, Abase, 0, k3);
        PIN(); BARB(); MFMAQ(4, 2, af, b1)                // P7

        if (more) { STAGE(Bs1h0, Bbase, 0, k3); VM4(); }
        PIN(); BARB(); MFMAQ(4, 0, af, b0)                // P8
    }

    const int lr4 = (lane >> 4) * 4;
#pragma unroll
    for (int mi = 0; mi < 8; ++mi) {
        int rowb = m0 + mi * 32 + wm * 16 + lr4;
#pragma unroll
        for (int ni = 0; ni < 4; ++ni) {
            int col = n0 + ni * 64 + wn * 16 + lrow;
            float bv = bias[col];
#pragma unroll
            for (int r = 0; r < 4; ++r) {
                int row = rowb + r;
                float val = acc[mi][ni][r] + bv;
                if (HAS_GATE) {
                    float g = bf2f(gate[(size_t)row * ldg + col]);
                    val *= g * sigf(g);
                }
                if (OUT_BF16)
                    ((short*)Cv)[(size_t)row * N + col] = f2bf(val);
                else
                    ((float*)Cv)[(size_t)row * N + col] = val;
            }
        }
    }
}

// ---------------- scan pass 1: 8-deep prefetch groups, grid (64,4,2) x 256 thr ----------------
__global__ __launch_bounds__(256) void chunk_reduce(
    const short* __restrict__ pre, float* __restrict__ sA, float* __restrict__ sBv)
{
    const int t = threadIdx.x;
    const int c = blockIdx.x;
    const int b = blockIdx.y;
    const int d0 = blockIdx.z * 512 + 2 * t;
    float A0 = 1.f, A1 = 1.f, B0 = 0.f, B1 = 0.f;
    size_t base = ((size_t)(b * LDIM) + c * LCHUNK) * NPROJ + d0;
    for (int i = 0; i < LCHUNK; i += 8) {
        uint z[8], dv[8];
#pragma unroll
        for (int k = 0; k < 8; ++k) {
            z[k]  = *(const uint*)&pre[base + (size_t)k * NPROJ];
            dv[k] = *(const uint*)&pre[base + (size_t)k * NPROJ + DDIM];
        }
#pragma unroll
        for (int k = 0; k < 8; ++k) {
            SCANSTEP(z[k], dv[k], B0, B1, A0, A1, 1)
        }
        base += 8 * NPROJ;
    }
    int idx = ((b * NCHUNK + c) << 10) + d0;
    *reinterpret_cast<float2*>(&sA[idx])  = make_float2(A0, A1);
    *reinterpret_cast<float2*>(&sBv[idx]) = make_float2(B0, B1);
}

// ------- scan pass 2 (fused prefix+apply): fold chunk summaries 0..c-1, then scan -------
__global__ __launch_bounds__(256) void chunk_apply(
    const short* __restrict__ pre, const float* __restrict__ sA,
    const float* __restrict__ sBv, const float* __restrict__ hidden,
    float* __restrict__ hout, short* __restrict__ hbf)
{
    const int t = threadIdx.x;
    const int c = blockIdx.x;
    const int b = blockIdx.y;
    const int d0 = blockIdx.z * 512 + 2 * t;

    float2 hv = *reinterpret_cast<const float2*>(&hidden[b * DDIM + d0]);
    float h0 = hv.x, h1 = hv.y;
    {
        int base_idx = (b * NCHUNK << 10) + d0;
        int k = 0;
        for (; k + 8 <= c; k += 8) {
            float2 a[8], v[8];
#pragma unroll
            for (int j = 0; j < 8; ++j) {
                int idx = base_idx + ((k + j) << 10);
                a[j] = *reinterpret_cast<const float2*>(&sA[idx]);
                v[j] = *reinterpret_cast<const float2*>(&sBv[idx]);
            }
#pragma unroll
            for (int j = 0; j < 8; ++j) {
                h0 = v[j].x + a[j].x * h0;
                h1 = v[j].y + a[j].y * h1;
            }
        }
        for (; k < c; ++k) {
            int idx = base_idx + (k << 10);
            float2 a = *reinterpret_cast<const float2*>(&sA[idx]);
            float2 v = *reinterpret_cast<const float2*>(&sBv[idx]);
            h0 = v.x + a.x * h0;
            h1 = v.y + a.y * h1;
        }
    }

    size_t base  = ((size_t)(b * LDIM) + c * LCHUNK) * NPROJ + d0;
    size_t obase = ((size_t)(b * LDIM) + c * LCHUNK) * DDIM + d0;
    for (int i = 0; i < LCHUNK; i += 8) {
        uint z[8], dv[8];
#pragma unroll
        for (int k = 0; k < 8; ++k) {
            z[k]  = *(const uint*)&pre[base + (size_t)k * NPROJ];
            dv[k] = *(const uint*)&pre[base + (size_t)k * NPROJ + DDIM];
        }
        float dummyA = 0.f, dummyB = 0.f;
#pragma unroll
        for (int k = 0; k < 8; ++k) {
            SCANSTEP(z[k], dv[k], h0, h1, dummyA, dummyB, 0)
            *reinterpret_cast<float2*>(&hout[obase + (size_t)k * DDIM]) =
                make_float2(h0, h1);
            *reinterpret_cast<uint*>(&hbf[obase + (size_t)k * DDIM]) =
                ((uint)(unsigned short)f2bf(h0)) |
                (((uint)(unsigned short)f2bf(h1)) << 16);
        }
        base += 8 * NPROJ;
        obase += 8 * DDIM;
    }
}

extern "C" void kernel_launch(void* const* d_in, const int* in_sizes, int n_in,
                              void* d_out, int out_size, void* d_ws, size_t ws_size,
                              hipStream_t stream) {
    const float* x      = (const float*)d_in[0];
    const float* hidden = (const float*)d_in[1];
    const float* W_ln_z = (const float*)d_in[2];
    const float* b_ln_z = (const float*)d_in[3];
    const float* W_dt   = (const float*)d_in[4];
    const float* b_dt   = (const float*)d_in[5];
    const float* W_y    = (const float*)d_in[6];
    const float* b_y    = (const float*)d_in[7];
    const float* W_g    = (const float*)d_in[8];
    const float* b_g    = (const float*)d_in[9];

    char* ws = (char*)d_ws;
    short* x_bf   = (short*)(ws + 0);                       // 33,554,432 (reused as h_bf)
    short* Wcat   = (short*)(ws + 33554432);                //  6,291,456
    short* Wy_bf  = (short*)(ws + 39845888);                //  2,097,152 (contiguous after Wcat)
    float* biascat= (float*)(ws + 41943040);                //     12,288
    short* pre    = (short*)(ws + 41955328);                // 100,663,296
    float* sA     = (float*)(ws + 142618624);               //  1,048,576
    float* sBv    = (float*)(ws + 143667200);               //  1,048,576

    fused_init<<<20484, 256, 0, stream>>>(x, W_ln_z, W_dt, W_g, W_y,
                                          b_ln_z, b_dt, b_g, x_bf, Wcat, biascat);

    gemm256<1, 0><<<dim3(NPROJ / 256, MROWS / 256), 512, 0, stream>>>(
        x_bf, Wcat, biascat, pre, MROWS, NPROJ, KDIM, nullptr, 0);

    float* y_out = (float*)d_out;
    float* h_out = (float*)d_out + (size_t)MROWS * DDIM;
    short* h_bf  = x_bf;
    chunk_reduce<<<dim3(NCHUNK, BDIM, 2), 256, 0, stream>>>(pre, sA, sBv);
    chunk_apply<<<dim3(NCHUNK, BDIM, 2), 256, 0, stream>>>(pre, sA, sBv, hidden,
                                                           h_out, h_bf);

    gemm256<0, 1><<<dim3(DDIM / 256, MROWS / 256), 512, 0, stream>>>(
        h_bf, Wy_bf, b_y, y_out, MROWS, DDIM, KDIM, pre + 2 * DDIM, NPROJ);
}